// Round 2
// baseline (428.957 us; speedup 1.0000x reference)
//
#include <hip/hip_runtime.h>
#include <hip/hip_bf16.h>

typedef __bf16 bf16x8 __attribute__((ext_vector_type(8)));
typedef float f32x4 __attribute__((ext_vector_type(4)));

static constexpr int Tn = 8192;
static constexpr int Cn = 1024;

#define DEVI __device__ __forceinline__

DEVI float bf2f(ushort u) { union { uint i; float f; } c; c.i = ((uint)u) << 16; return c.f; }
DEVI ushort f2bf(float f) {
  uint x = __builtin_bit_cast(uint, f);
  x += 0x7fffu + ((x >> 16) & 1u);   // RNE
  return (ushort)(x >> 16);
}

typedef const __attribute__((address_space(1))) void glb_v;
typedef __attribute__((address_space(3))) void lds_v;

#define BAR()  __builtin_amdgcn_s_barrier()
#define LGK0() asm volatile("s_waitcnt lgkmcnt(0)" ::: "memory")
#define VM4()  asm volatile("s_waitcnt vmcnt(4)" ::: "memory")
#define VM0()  asm volatile("s_waitcnt vmcnt(0)" ::: "memory")
#define PRIO1() __builtin_amdgcn_s_setprio(1)
#define PRIO0() __builtin_amdgcn_s_setprio(0)

// ---------------------------------------------------------------- cast + concat
__global__ __launch_bounds__(256) void cast_all(
    const float* __restrict__ x, const float* __restrict__ wq, const float* __restrict__ wk,
    const float* __restrict__ wv, const float* __restrict__ wp,
    const float* __restrict__ bq, const float* __restrict__ bk, const float* __restrict__ bv,
    ushort* __restrict__ xb, ushort* __restrict__ wqkv, ushort* __restrict__ wpb,
    float* __restrict__ bqkv)
{
  const long long NX = (long long)Tn * Cn;      // 8388608
  const long long NW = (long long)Cn * Cn;      // 1048576 = 2^20
  if (blockIdx.x >= 12288) {   // bias concat (3 blocks)
    int id = ((blockIdx.x - 12288) * 256 + threadIdx.x) * 4;
#pragma unroll
    for (int e = 0; e < 4; ++e) {
      int j = id + e;
      if (j < 3 * Cn) bqkv[j] = j < Cn ? bq[j] : (j < 2 * Cn ? bk[j - Cn] : bv[j - 2 * Cn]);
    }
    return;
  }
  long long i = ((long long)blockIdx.x * 256 + threadIdx.x) * 4;
  const float* src; ushort* dst; long long off;
  if (i < NX) { src = x; dst = xb; off = i; }
  else {
    long long r = i - NX; int seg = (int)(r >> 20); off = r & (NW - 1);
    if (seg < 3) { src = seg == 0 ? wq : seg == 1 ? wk : wv; dst = wqkv + (size_t)seg * NW; }
    else         { src = wp; dst = wpb; }
  }
  float4 v = *reinterpret_cast<const float4*>(src + off);
  ushort4 o; o.x = f2bf(v.x); o.y = f2bf(v.y); o.z = f2bf(v.z); o.w = f2bf(v.w);
  *reinterpret_cast<ushort4*>(dst + off) = o;
}

// ---------------------------------------------------------------- 8-phase GEMM
// C[M,N] = A[M,K] @ Bt[N,K]^T, bf16 in, fp32 acc. 8 waves (2M x 4N), BK=64,
// double-buffered LDS, chunk-XOR swizzle (verified 0 bank conflicts), counted
// vmcnt(4) at phases 4/8 only (T4), setprio around MFMA clusters (T5).
// PVMODE: grid.y = M/BM/2 row-pairs; block does rows (2*gy-1-by) then (by),
// with causal K-limit — per-block K total is constant (load balance).
template<int BM, int BN, bool OUT_BF16, bool HAS_BIAS, bool CAUSAL_SKIP, bool PVMODE>
__global__ __launch_bounds__(512, 2)
void gemm8(const ushort* __restrict__ A, const ushort* __restrict__ Bt,
           const float* __restrict__ bias, void* __restrict__ outp,
           int M, int N, int K, int lda, int ldb, int ldc, float scale)
{
  constexpr int ASZ = (BM / 2) * 64;          // elems per A half-tile
  constexpr int BSZ = (BN / 2) * 64;
  constexpr int TOT = 2 * ASZ + 2 * BSZ;
  constexpr int LA = BM / 128;                // loads/thread per A half
  constexpr int LB = BN / 128;
  constexpr int MREP = BM / 32;               // per-wave M fragments
  constexpr int NREP = BN / 64;               // per-wave N fragments (=4)
  constexpr int MH = MREP / 2;

  __shared__ __align__(16) ushort sm[2 * TOT];

  const int tid = threadIdx.x;
  const int lane = tid & 63, wid = tid >> 6;
  const int wm = wid >> 2, wn = wid & 3;
  const int ln15 = lane & 15, lsec = lane >> 4;
  const int bx = blockIdx.x;

  if (CAUSAL_SKIP && (int)blockIdx.y < bx) return;

  const ushort* aB[2] = { &sm[0 * TOT + wm * ASZ], &sm[1 * TOT + wm * ASZ] };
  const ushort* bB[2] = { &sm[0 * TOT + 2 * ASZ + (wn >> 1) * BSZ],
                          &sm[1 * TOT + 2 * ASZ + (wn >> 1) * BSZ] };

  const int npairs = PVMODE ? 2 : 1;
  for (int pr = 0; pr < npairs; ++pr) {
    const int by = PVMODE ? (pr == 0 ? (int)(2 * gridDim.y - 1 - blockIdx.y)
                                     : (int)blockIdx.y)
                          : (int)blockIdx.y;
    int NT = K >> 6;
    if (PVMODE) { int kl = (by + 1) * BM; NT = (kl < K ? kl : K) >> 6; }
    const int rowA0 = by * BM, col0 = bx * BN;

    auto stageA = [&](int b, int h, int t) {
      const int k0 = (t < NT) ? (t << 6) : 0;
#pragma unroll
      for (int i = 0; i < LA; ++i) {
        int slot = tid + i * 512;
        int row = slot >> 3, kc = slot & 7;
        int kcs = kc ^ (row & 7);
        const ushort* g = A + (size_t)(rowA0 + h * (BM / 2) + row) * (size_t)lda + (k0 + kcs * 8);
        __builtin_amdgcn_global_load_lds((glb_v*)g, (lds_v*)(&sm[b * TOT + h * ASZ + slot * 8]), 16, 0, 0);
      }
    };
    auto stageB = [&](int b, int h, int t) {
      const int k0 = (t < NT) ? (t << 6) : 0;
#pragma unroll
      for (int i = 0; i < LB; ++i) {
        int slot = tid + i * 512;
        int row = slot >> 3, kc = slot & 7;
        int kcs = kc ^ (row & 7);
        const ushort* g = Bt + (size_t)(col0 + h * (BN / 2) + row) * (size_t)ldb + (k0 + kcs * 8);
        __builtin_amdgcn_global_load_lds((glb_v*)g, (lds_v*)(&sm[b * TOT + 2 * ASZ + h * BSZ + slot * 8]), 16, 0, 0);
      }
    };
    auto rdA = [&](const ushort* base, int mi, int ks) -> bf16x8 {
      int r = mi * 16 + ln15, kc = ks * 4 + lsec;
      return *reinterpret_cast<const bf16x8*>(base + (r * 8 + (kc ^ (r & 7))) * 8);
    };
    auto rdB = [&](const ushort* base, int ni, int ks) -> bf16x8 {
      int c = (wn & 1) * 64 + ni * 16 + ln15, kc = ks * 4 + lsec;
      return *reinterpret_cast<const bf16x8*>(base + (c * 8 + (kc ^ (c & 7))) * 8);
    };

    f32x4 acc[MREP][NREP] = {};
    bf16x8 a[2 * MH], bl[4], bh[4];

    auto quad = [&](int mb, int nb, bf16x8* bb) {
#pragma unroll
      for (int i = 0; i < MH; ++i)
#pragma unroll
        for (int j = 0; j < 2; ++j) {
          acc[mb + i][nb + j] = __builtin_amdgcn_mfma_f32_16x16x32_bf16(a[2 * i], bb[2 * j], acc[mb + i][nb + j], 0, 0, 0);
          acc[mb + i][nb + j] = __builtin_amdgcn_mfma_f32_16x16x32_bf16(a[2 * i + 1], bb[2 * j + 1], acc[mb + i][nb + j], 0, 0, 0);
        }
    };
#define RD_A_LO(b) { _Pragma("unroll") for (int i = 0; i < MH; ++i) { a[2*i] = rdA(aB[b], i, 0); a[2*i+1] = rdA(aB[b], i, 1); } }
#define RD_A_HI(b) { _Pragma("unroll") for (int i = 0; i < MH; ++i) { a[2*i] = rdA(aB[b], MH + i, 0); a[2*i+1] = rdA(aB[b], MH + i, 1); } }
#define RD_B_LO(b) { _Pragma("unroll") for (int i = 0; i < 2; ++i) { bl[2*i] = rdB(bB[b], i, 0); bl[2*i+1] = rdB(bB[b], i, 1); } }
#define RD_B_HI(b) { _Pragma("unroll") for (int i = 0; i < 2; ++i) { bh[2*i] = rdB(bB[b], 2 + i, 0); bh[2*i+1] = rdB(bB[b], 2 + i, 1); } }

    // ---- prologue: tile0 (all 4 halves) + tile1 (B halves); first 4 halves must land
    stageB(0, 0, 0); stageB(0, 1, 0); stageA(0, 0, 0); stageA(0, 1, 0);
    stageB(1, 0, 1); stageB(1, 1, 1);
    VM4(); BAR();

    const int NG = NT >> 1;
    for (int g = 0; g < NG; ++g) {
      const int t = 2 * g;
      // ph1: tile t (buf0) Mlo x Nlo | stage A0(t+1)->buf1
      RD_A_LO(0); RD_B_LO(0); stageA(1, 0, t + 1);
      BAR(); LGK0(); PRIO1(); quad(0, 0, bl); PRIO0(); BAR();
      // ph2: Mlo x Nhi | stage A1(t+1)->buf1
      RD_B_HI(0); stageA(1, 1, t + 1);
      BAR(); LGK0(); PRIO1(); quad(0, 2, bh); PRIO0(); BAR();
      // ph3: Mhi x Nhi | stage B0(t+2)->buf0 (B(t) reads ended ph2)
      RD_A_HI(0); stageB(0, 0, t + 2);
      BAR(); LGK0(); PRIO1(); quad(MH, 2, bh); PRIO0(); BAR();
      // ph4: Mhi x Nlo | stage B1(t+2)->buf0 | counted wait: A(t+1)+B(t+1) landed
      stageB(0, 1, t + 2); VM4();
      BAR(); LGK0(); PRIO1(); quad(MH, 0, bl); PRIO0(); BAR();
      // ph5: tile t+1 (buf1) Mlo x Nlo | stage A0(t+2)->buf0 (A(t) reads ended ph3)
      RD_A_LO(1); RD_B_LO(1); stageA(0, 0, t + 2);
      BAR(); LGK0(); PRIO1(); quad(0, 0, bl); PRIO0(); BAR();
      // ph6: Mlo x Nhi | stage A1(t+2)->buf0
      RD_B_HI(1); stageA(0, 1, t + 2);
      BAR(); LGK0(); PRIO1(); quad(0, 2, bh); PRIO0(); BAR();
      // ph7: Mhi x Nhi | stage B0(t+3)->buf1 (B(t+1) reads ended ph6)
      RD_A_HI(1); stageB(1, 0, t + 3);
      BAR(); LGK0(); PRIO1(); quad(MH, 2, bh); PRIO0(); BAR();
      // ph8: Mhi x Nlo | stage B1(t+3)->buf1 | counted wait: tile t+2 fully landed
      stageB(1, 1, t + 3); VM4();
      BAR(); LGK0(); PRIO1(); quad(MH, 0, bl); PRIO0(); BAR();
    }

    // ---- epilogue: C col = lane&15 (+ni*16), row = lsec*4 + j (+mi*16)
#pragma unroll
    for (int mi = 0; mi < MREP; ++mi)
#pragma unroll
      for (int ni = 0; ni < NREP; ++ni) {
        int col = col0 + wn * 64 + ni * 16 + ln15;
        float bv = HAS_BIAS ? bias[col] : 0.f;
        int r0 = rowA0 + wm * (BM / 2) + mi * 16 + lsec * 4;
        f32x4 v = acc[mi][ni];
#pragma unroll
        for (int j = 0; j < 4; ++j) {
          float val = v[j] * scale + bv;
          if (OUT_BF16) ((ushort*)outp)[(size_t)(r0 + j) * (size_t)ldc + col] = f2bf(val);
          else          ((float*)outp)[(size_t)(r0 + j) * (size_t)ldc + col] = val;
        }
      }
    if (PVMODE && pr == 0) { VM0(); BAR(); }   // clean vmcnt ledger for pair 2
#undef RD_A_LO
#undef RD_A_HI
#undef RD_B_LO
#undef RD_B_HI
  }
  VM0();   // clamped stages must land before LDS is reassigned
}

// ---------------------------------------------------------------- transpose (bf16), 64x64 tiles
__global__ __launch_bounds__(256) void transpose64(const ushort* __restrict__ in,
                                                   ushort* __restrict__ out,
                                                   int ldin, int ldout)
{
  __shared__ ushort tile[64][65];
  const int c0 = blockIdx.x * 64, r0 = blockIdx.y * 64;
  const int t = threadIdx.x;
#pragma unroll
  for (int i = t; i < 512; i += 256) {
    int r = i >> 3, kc = i & 7;
    uint4 v = *reinterpret_cast<const uint4*>(in + (size_t)(r0 + r) * ldin + c0 + kc * 8);
    const ushort* u = reinterpret_cast<const ushort*>(&v);
#pragma unroll
    for (int j = 0; j < 8; ++j) tile[r][kc * 8 + j] = u[j];
  }
  __syncthreads();
#pragma unroll
  for (int i = t; i < 512; i += 256) {
    int c = i >> 3, rc = i & 7;
    union { uint4 v; ushort u[8]; } pk;
#pragma unroll
    for (int j = 0; j < 8; ++j) pk.u[j] = tile[rc * 8 + j][c];
    *reinterpret_cast<uint4*>(out + (size_t)(c0 + c) * ldout + r0 + rc * 8) = pk.v;
  }
}

// ---------------------------------------------------------------- causal softmax, in place
__global__ __launch_bounds__(256) void softmax_causal(ushort* __restrict__ S, int Td)
{
  const int t = blockIdx.x;
  const int tid = threadIdx.x;
  ushort* row = S + (size_t)t * Td;
  const int L = t + 1;
  const int Lv = L & ~7;

  float sum = 0.f;
  for (int j = tid * 8; j < Lv; j += 2048) {
    uint4 v = *reinterpret_cast<const uint4*>(row + j);
    const ushort* u = reinterpret_cast<const ushort*>(&v);
#pragma unroll
    for (int e = 0; e < 8; ++e) sum += __expf(bf2f(u[e]));
  }
  for (int j = Lv + tid; j < L; j += 256) sum += __expf(bf2f(row[j]));

#pragma unroll
  for (int off = 32; off; off >>= 1) sum += __shfl_down(sum, off);
  __shared__ float red[4];
  if ((tid & 63) == 0) red[tid >> 6] = sum;
  __syncthreads();
  const float inv = 1.f / (red[0] + red[1] + red[2] + red[3]);

  for (int j = tid * 8; j < Lv; j += 2048) {
    uint4 v = *reinterpret_cast<const uint4*>(row + j);
    union { uint4 v; ushort u[8]; } pk;
    const ushort* u = reinterpret_cast<const ushort*>(&v);
#pragma unroll
    for (int e = 0; e < 8; ++e) pk.u[e] = f2bf(__expf(bf2f(u[e])) * inv);
    *reinterpret_cast<uint4*>(row + j) = pk.v;
  }
  for (int j = Lv + tid; j < L; j += 256) row[j] = f2bf(__expf(bf2f(row[j])) * inv);

  const int Za = (L + 7) & ~7;
  for (int j = L + tid; j < Za; j += 256) row[j] = 0;
  uint4 z; z.x = z.y = z.z = z.w = 0u;
  for (int j = Za + tid * 8; j < Td; j += 2048) *reinterpret_cast<uint4*>(row + j) = z;
}

// ---------------------------------------------------------------- launch
extern "C" void kernel_launch(void* const* d_in, const int* in_sizes, int n_in,
                              void* d_out, int out_size, void* d_ws, size_t ws_size,
                              hipStream_t stream)
{
  (void)in_sizes; (void)n_in; (void)out_size; (void)ws_size;
  const float* x  = (const float*)d_in[0];
  const float* Wq = (const float*)d_in[1];
  const float* bq = (const float*)d_in[2];
  const float* Wk = (const float*)d_in[3];
  const float* bk = (const float*)d_in[4];
  const float* Wv = (const float*)d_in[5];
  const float* bv = (const float*)d_in[6];
  const float* Wp = (const float*)d_in[7];
  const float* bp = (const float*)d_in[8];

  char* w = (char*)d_ws;
  const size_t TC = (size_t)Tn * Cn * 2, CC = (size_t)Cn * Cn * 2;
  ushort* xb   = (ushort*)w; w += TC;                    // 16 MB
  ushort* Wqkv = (ushort*)w; w += 3 * CC;                // 6 MB
  ushort* wpb  = (ushort*)w; w += CC;                    // 2 MB
  float*  bqkv = (float*)w;  w += 3 * Cn * 4 + 4096;     // 12 KB
  ushort* QKV  = (ushort*)w; w += 3 * TC;                // 48 MB
  ushort* Vt   = (ushort*)w; w += TC;                    // 16 MB
  ushort* Yb   = (ushort*)w; w += TC;                    // 16 MB
  ushort* S    = (ushort*)w; w += (size_t)Tn * Tn * 2;   // 128 MB

  cast_all<<<12291, 256, 0, stream>>>(x, Wq, Wk, Wv, Wp, bq, bk, bv, xb, Wqkv, wpb, bqkv);

  // QKV fused: [8192,3072] = xb @ Wqkv^T + bqkv   (768 blocks = 3 exact rounds)
  gemm8<128, 256, true, true, false, false><<<dim3(12, 64), 512, 0, stream>>>(
      xb, Wqkv, bqkv, QKV, Tn, 3 * Cn, Cn, Cn, Cn, 3 * Cn, 1.0f);

  // V^T for the PV GEMM
  transpose64<<<dim3(Cn / 64, Tn / 64), 256, 0, stream>>>(QKV + 2 * Cn, Vt, 3 * Cn, Tn);

  // S = Q @ K^T / 32  (causal block skip)
  gemm8<256, 256, true, false, true, false><<<dim3(Tn / 256, Tn / 256), 512, 0, stream>>>(
      QKV, QKV + Cn, nullptr, S, Tn, Tn, Cn, 3 * Cn, 3 * Cn, Tn, 0.03125f);

  softmax_causal<<<Tn, 256, 0, stream>>>(S, Tn);

  // Y = P @ V  (paired causal K-limit: rows (63-gy)*128 then gy*128 per block)
  gemm8<128, 256, true, false, false, true><<<dim3(Cn / 256, Tn / 256), 512, 0, stream>>>(
      S, Vt, nullptr, Yb, Tn, Cn, Tn, Tn, Tn, Cn, 1.0f);

  // out = Y @ Wp^T + bp   (fp32 out)
  gemm8<128, 256, false, true, false, false><<<dim3(Cn / 256, Tn / 128), 512, 0, stream>>>(
      Yb, wpb, bp, d_out, Tn, Cn, Cn, Cn, Cn, Cn, 1.0f);
}

// Round 3
// 379.778 us; speedup vs baseline: 1.1295x; 1.1295x over previous
//
#include <hip/hip_runtime.h>
#include <hip/hip_bf16.h>

typedef __bf16 bf16x8 __attribute__((ext_vector_type(8)));
typedef float f32x4 __attribute__((ext_vector_type(4)));

static constexpr int Tn = 8192;
static constexpr int Cn = 1024;

#define DEVI __device__ __forceinline__

DEVI float bf2f(ushort u) { union { uint i; float f; } c; c.i = ((uint)u) << 16; return c.f; }
DEVI ushort f2bf(float f) {
  uint x = __builtin_bit_cast(uint, f);
  x += 0x7fffu + ((x >> 16) & 1u);   // RNE
  return (ushort)(x >> 16);
}

typedef const __attribute__((address_space(1))) void glb_v;
typedef __attribute__((address_space(3))) void lds_v;

#define BAR()  __builtin_amdgcn_s_barrier()
#define SCH0() __builtin_amdgcn_sched_barrier(0)
#define LGK0() asm volatile("s_waitcnt lgkmcnt(0)" ::: "memory")
#define VM0()  asm volatile("s_waitcnt vmcnt(0)" ::: "memory")

// ---------------------------------------------------------------- cast + concat
__global__ __launch_bounds__(256) void cast_all(
    const float* __restrict__ x, const float* __restrict__ wq, const float* __restrict__ wk,
    const float* __restrict__ wv, const float* __restrict__ wp,
    const float* __restrict__ bq, const float* __restrict__ bk, const float* __restrict__ bv,
    ushort* __restrict__ xb, ushort* __restrict__ wqkv, ushort* __restrict__ wpb,
    float* __restrict__ bqkv)
{
  const long long NX = (long long)Tn * Cn;
  const long long NW = (long long)Cn * Cn;      // 2^20
  if (blockIdx.x >= 12288) {   // bias concat
    int id = ((blockIdx.x - 12288) * 256 + threadIdx.x) * 4;
#pragma unroll
    for (int e = 0; e < 4; ++e) {
      int j = id + e;
      if (j < 3 * Cn) bqkv[j] = j < Cn ? bq[j] : (j < 2 * Cn ? bk[j - Cn] : bv[j - 2 * Cn]);
    }
    return;
  }
  long long i = ((long long)blockIdx.x * 256 + threadIdx.x) * 4;
  const float* src; ushort* dst; long long off;
  if (i < NX) { src = x; dst = xb; off = i; }
  else {
    long long r = i - NX; int seg = (int)(r >> 20); off = r & (NW - 1);
    if (seg < 3) { src = seg == 0 ? wq : seg == 1 ? wk : wv; dst = wqkv + (size_t)seg * NW; }
    else         { src = wp; dst = wpb; }
  }
  float4 v = *reinterpret_cast<const float4*>(src + off);
  ushort4 o; o.x = f2bf(v.x); o.y = f2bf(v.y); o.z = f2bf(v.z); o.w = f2bf(v.w);
  *reinterpret_cast<ushort4*>(dst + off) = o;
}

// ---------------------------------------------------------------- pipelined GEMM
// C[M,N] = A[M,K] @ Bt[N,K]^T.  Register-double-buffered 32-k-slice pipeline:
// reads for slice s+1 issue before the MFMA cluster of slice s (counted lgkmcnt
// by the compiler), staging stays >=1 tile in flight (counted vmcnt, never 0
// in-loop). Chunk-XOR LDS swizzle (0 bank conflicts, verified R1/R2).
template<int BM, int BN, int WM, int WN, bool OUT_BF16, bool HAS_BIAS, bool CAUSAL_SKIP, bool PVMODE>
__global__ __launch_bounds__(WM * WN * 64, 2)
void gemm_pipe(const ushort* __restrict__ A, const ushort* __restrict__ Bt,
               const float* __restrict__ bias, void* __restrict__ outp,
               int K, int lda, int ldb, int ldc, float scale)
{
  constexpr int NTHR = WM * WN * 64;
  constexpr int RM = BM / WM, CN = BN / WN;
  constexpr int MREP = RM / 16, NREP = CN / 16;
  constexpr int LA = BM * 64 / (NTHR * 8), LB = BN * 64 / (NTHR * 8);
  constexpr int VMN = LA + LB;           // steady-state in-flight vm instructions
  constexpr int TSZ = (BM + BN) * 64;    // elems per LDS tile buffer

  __shared__ __align__(16) ushort sm[2 * TSZ];

  const int tid = threadIdx.x, lane = tid & 63, wid = tid >> 6;
  const int wm = wid / WN, wn = wid % WN;
  const int ln15 = lane & 15, lsec = lane >> 4;
  const int bx = blockIdx.x;
  int by = blockIdx.y;
  if (CAUSAL_SKIP && bx * BN > by * BM + (BM - 1)) return;   // fully above diagonal
  if (PVMODE) by = gridDim.y - 1 - by;                       // longest-K blocks first

  const int rowA0 = by * BM, col0 = bx * BN;
  int NT = K >> 6;
  if (PVMODE) { int kl = (by + 1) * BM; if (kl < K) NT = kl >> 6; }

  auto vmw = [&]() {
    if constexpr (VMN == 6)      asm volatile("s_waitcnt vmcnt(6)" ::: "memory");
    else if constexpr (VMN == 8) asm volatile("s_waitcnt vmcnt(8)" ::: "memory");
    else static_assert(VMN == 6 || VMN == 8, "unsupported stage width");
  };

  auto stage = [&](int t, int b) {
    const int tt = t < NT ? t : NT - 1;
    const int k0 = tt << 6;
#pragma unroll
    for (int i = 0; i < LA; ++i) {
      int s = tid + i * NTHR; int row = s >> 3, kc = s & 7; int kcs = kc ^ (row & 7);
      const ushort* g = A + (size_t)(rowA0 + row) * (size_t)lda + (k0 + kcs * 8);
      __builtin_amdgcn_global_load_lds((glb_v*)g, (lds_v*)(&sm[b * TSZ + s * 8]), 16, 0, 0);
    }
#pragma unroll
    for (int i = 0; i < LB; ++i) {
      int s = tid + i * NTHR; int row = s >> 3, kc = s & 7; int kcs = kc ^ (row & 7);
      const ushort* g = Bt + (size_t)(col0 + row) * (size_t)ldb + (k0 + kcs * 8);
      __builtin_amdgcn_global_load_lds((glb_v*)g, (lds_v*)(&sm[b * TSZ + BM * 64 + s * 8]), 16, 0, 0);
    }
  };

  auto rdAB = [&](bf16x8 (&Af)[MREP], bf16x8 (&Bf)[NREP], int b, int ks) {
    const ushort* Ab_ = &sm[b * TSZ];
    const ushort* Bb_ = &sm[b * TSZ + BM * 64];
#pragma unroll
    for (int mi = 0; mi < MREP; ++mi) {
      int r = wm * RM + mi * 16 + ln15, kc = ks * 4 + lsec;
      Af[mi] = *reinterpret_cast<const bf16x8*>(&Ab_[(r * 8 + (kc ^ (r & 7))) * 8]);
    }
#pragma unroll
    for (int ni = 0; ni < NREP; ++ni) {
      int c = wn * CN + ni * 16 + ln15, kc = ks * 4 + lsec;
      Bf[ni] = *reinterpret_cast<const bf16x8*>(&Bb_[(c * 8 + (kc ^ (c & 7))) * 8]);
    }
  };

  f32x4 acc[MREP][NREP] = {};
  bf16x8 Aa[MREP], Ba[NREP], Az[MREP], Bz[NREP];

  auto mmacA = [&]() {
#pragma unroll
    for (int mi = 0; mi < MREP; ++mi)
#pragma unroll
      for (int ni = 0; ni < NREP; ++ni)
        acc[mi][ni] = __builtin_amdgcn_mfma_f32_16x16x32_bf16(Aa[mi], Ba[ni], acc[mi][ni], 0, 0, 0);
  };
  auto mmacZ = [&]() {
#pragma unroll
    for (int mi = 0; mi < MREP; ++mi)
#pragma unroll
      for (int ni = 0; ni < NREP; ++ni)
        acc[mi][ni] = __builtin_amdgcn_mfma_f32_16x16x32_bf16(Az[mi], Bz[ni], acc[mi][ni], 0, 0, 0);
  };

  // prologue: tiles 0,1 in flight; wait tile0 landed; prefetch slice0(0)
  stage(0, 0); stage(1, 1);
  vmw(); BAR(); SCH0();
  rdAB(Aa, Ba, 0, 0);
  SCH0();

  int cur = 0;
  for (int t = 0; t < NT; ++t) {
    rdAB(Az, Bz, cur, 1);         // slice1(t) reads — in flight during mmacA
    SCH0();
    mmacA();                      // slice0(t): compiler waits lgkmcnt(<slice1 count>)
    SCH0();
    LGK0();                       // all my tile-t reads done
    BAR();                        // all waves done reading buf[cur]
    SCH0();
    stage(t + 2, cur);            // overwrite buf[cur] with tile t+2
    vmw();                        // my tile t+1 loads landed (t+2 still in flight)
    BAR();                        // everyone's t+1 landed -> buf[cur^1] valid
    SCH0();
    if (t + 1 < NT) rdAB(Aa, Ba, cur ^ 1, 0);   // slice0(t+1) — in flight during mmacZ
    SCH0();
    mmacZ();                      // slice1(t)
    SCH0();
    cur ^= 1;
  }
  VM0();

  // epilogue: C col = lane&15 (+ni*16), row = lsec*4 + j (+mi*16)
#pragma unroll
  for (int mi = 0; mi < MREP; ++mi)
#pragma unroll
    for (int ni = 0; ni < NREP; ++ni) {
      int col = col0 + wn * CN + ni * 16 + ln15;
      float bv = HAS_BIAS ? bias[col] : 0.f;
      int r0 = rowA0 + wm * RM + mi * 16 + lsec * 4;
      f32x4 v = acc[mi][ni];
#pragma unroll
      for (int j = 0; j < 4; ++j) {
        float val = v[j] * scale + bv;
        if (OUT_BF16) ((ushort*)outp)[(size_t)(r0 + j) * (size_t)ldc + col] = f2bf(val);
        else          ((float*)outp)[(size_t)(r0 + j) * (size_t)ldc + col] = val;
      }
    }
}

// ---------------------------------------------------------------- transpose (bf16), 64x64 tiles
__global__ __launch_bounds__(256) void transpose64(const ushort* __restrict__ in,
                                                   ushort* __restrict__ out,
                                                   int ldin, int ldout)
{
  __shared__ ushort tile[64][65];
  const int c0 = blockIdx.x * 64, r0 = blockIdx.y * 64;
  const int t = threadIdx.x;
#pragma unroll
  for (int i = t; i < 512; i += 256) {
    int r = i >> 3, kc = i & 7;
    uint4 v = *reinterpret_cast<const uint4*>(in + (size_t)(r0 + r) * ldin + c0 + kc * 8);
    const ushort* u = reinterpret_cast<const ushort*>(&v);
#pragma unroll
    for (int j = 0; j < 8; ++j) tile[r][kc * 8 + j] = u[j];
  }
  __syncthreads();
#pragma unroll
  for (int i = t; i < 512; i += 256) {
    int c = i >> 3, rc = i & 7;
    union { uint4 v; ushort u[8]; } pk;
#pragma unroll
    for (int j = 0; j < 8; ++j) pk.u[j] = tile[rc * 8 + j][c];
    *reinterpret_cast<uint4*>(out + (size_t)(c0 + c) * ldout + r0 + rc * 8) = pk.v;
  }
}

// ---------------------------------------------------------------- causal softmax, in place
__global__ __launch_bounds__(256) void softmax_causal(ushort* __restrict__ S, int Td)
{
  const int t = blockIdx.x;
  const int tid = threadIdx.x;
  ushort* row = S + (size_t)t * Td;
  const int L = t + 1;
  const int Lv = L & ~7;

  float sum = 0.f;
  for (int j = tid * 8; j < Lv; j += 2048) {
    uint4 v = *reinterpret_cast<const uint4*>(row + j);
    const ushort* u = reinterpret_cast<const ushort*>(&v);
#pragma unroll
    for (int e = 0; e < 8; ++e) sum += __expf(bf2f(u[e]));
  }
  for (int j = Lv + tid; j < L; j += 256) sum += __expf(bf2f(row[j]));

#pragma unroll
  for (int off = 32; off; off >>= 1) sum += __shfl_down(sum, off);
  __shared__ float red[4];
  if ((tid & 63) == 0) red[tid >> 6] = sum;
  __syncthreads();
  const float inv = 1.f / (red[0] + red[1] + red[2] + red[3]);

  for (int j = tid * 8; j < Lv; j += 2048) {
    uint4 v = *reinterpret_cast<const uint4*>(row + j);
    union { uint4 v; ushort u[8]; } pk;
    const ushort* u = reinterpret_cast<const ushort*>(&v);
#pragma unroll
    for (int e = 0; e < 8; ++e) pk.u[e] = f2bf(__expf(bf2f(u[e])) * inv);
    *reinterpret_cast<uint4*>(row + j) = pk.v;
  }
  for (int j = Lv + tid; j < L; j += 256) row[j] = f2bf(__expf(bf2f(row[j])) * inv);

  const int Za = (L + 7) & ~7;
  for (int j = L + tid; j < Za; j += 256) row[j] = 0;
  uint4 z; z.x = z.y = z.z = z.w = 0u;
  for (int j = Za + tid * 8; j < Td; j += 2048) *reinterpret_cast<uint4*>(row + j) = z;
}

// ---------------------------------------------------------------- launch
extern "C" void kernel_launch(void* const* d_in, const int* in_sizes, int n_in,
                              void* d_out, int out_size, void* d_ws, size_t ws_size,
                              hipStream_t stream)
{
  (void)in_sizes; (void)n_in; (void)out_size; (void)ws_size;
  const float* x  = (const float*)d_in[0];
  const float* Wq = (const float*)d_in[1];
  const float* bq = (const float*)d_in[2];
  const float* Wk = (const float*)d_in[3];
  const float* bk = (const float*)d_in[4];
  const float* Wv = (const float*)d_in[5];
  const float* bv = (const float*)d_in[6];
  const float* Wp = (const float*)d_in[7];
  const float* bp = (const float*)d_in[8];

  char* w = (char*)d_ws;
  const size_t TC = (size_t)Tn * Cn * 2, CC = (size_t)Cn * Cn * 2;
  ushort* xb   = (ushort*)w; w += TC;                    // 16 MB
  ushort* Wqkv = (ushort*)w; w += 3 * CC;                // 6 MB
  ushort* wpb  = (ushort*)w; w += CC;                    // 2 MB
  float*  bqkv = (float*)w;  w += 3 * Cn * 4 + 4096;     // 12 KB
  ushort* QKV  = (ushort*)w; w += 3 * TC;                // 48 MB
  ushort* Vt   = (ushort*)w; w += TC;                    // 16 MB
  ushort* Yb   = (ushort*)w; w += TC;                    // 16 MB
  ushort* S    = (ushort*)w; w += (size_t)Tn * Tn * 2;   // 128 MB

  cast_all<<<12291, 256, 0, stream>>>(x, Wq, Wk, Wv, Wp, bq, bk, bv, xb, Wqkv, wpb, bqkv);

  // QKV fused: [8192,3072] = xb @ Wqkv^T + bqkv   (grid 768 = 3 exact rounds)
  gemm_pipe<256, 128, 2, 4, true, true, false, false><<<dim3(24, 32), 512, 0, stream>>>(
      xb, Wqkv, bqkv, QKV, Cn, Cn, Cn, 3 * Cn, 1.0f);

  // V^T for the PV GEMM
  transpose64<<<dim3(Cn / 64, Tn / 64), 256, 0, stream>>>(QKV + 2 * Cn, Vt, 3 * Cn, Tn);

  // S = Q @ K^T / 32  (1056 active blocks)
  gemm_pipe<256, 128, 2, 4, true, false, true, false><<<dim3(64, 32), 512, 0, stream>>>(
      QKV, QKV + Cn, nullptr, S, Cn, 3 * Cn, 3 * Cn, Tn, 0.03125f);

  softmax_causal<<<Tn, 256, 0, stream>>>(S, Tn);

  // Y = P @ V  (128^2 4-wave, 2 blocks/CU, longest-K first, causal K-limit)
  gemm_pipe<128, 128, 2, 2, true, false, false, true><<<dim3(8, 64), 256, 0, stream>>>(
      S, Vt, nullptr, Yb, Tn, Tn, Tn, Cn, 1.0f);

  // out = Y @ Wp^T + bp   (fp32 out, grid 256 exact)
  gemm_pipe<256, 128, 2, 4, false, true, false, false><<<dim3(8, 32), 512, 0, stream>>>(
      Yb, wpb, bp, d_out, Cn, Cn, Cn, Cn, 1.0f);
}